// Round 16
// baseline (367.949 us; speedup 1.0000x reference)
//
#include <hip/hip_runtime.h>

#define NF 768
#define D1 10
#define D2 128
#define BM 64

typedef __attribute__((ext_vector_type(8))) short bf16x8;
typedef __attribute__((ext_vector_type(16))) float f32x16;

static __device__ __forceinline__ float sigf(float v){ return 1.0f/(1.0f+__expf(-v)); }
static __device__ __forceinline__ float tanhfast(float v){ return 2.0f/(1.0f+__expf(-2.0f*v)) - 1.0f; }
static __device__ __forceinline__ short f2bf(float f){
    unsigned u = __float_as_uint(f);
    u += 0x7fffu + ((u>>16)&1u);
    return (short)(u>>16);
}
static __device__ __forceinline__ float bf2f(ushort h){
    return __uint_as_float(((unsigned)h)<<16);
}

static __device__ __forceinline__ void gload16(const void* g, void* l){
    __builtin_amdgcn_global_load_lds(
        (const __attribute__((address_space(1))) unsigned int*)(unsigned long long)g,
        (__attribute__((address_space(3))) unsigned int*)(unsigned long long)l,
        16, 0, 0);
}

static __device__ __forceinline__ short4 cvt4(float4 a){
    unsigned u0,u1;
    asm("v_cvt_pk_bf16_f32 %0, %1, %2" : "=v"(u0) : "v"(a.x), "v"(a.y));
    asm("v_cvt_pk_bf16_f32 %0, %1, %2" : "=v"(u1) : "v"(a.z), "v"(a.w));
    union { unsigned u[2]; short4 s; } r;
    r.u[0]=u0; r.u[1]=u1;
    return r.s;
}

// ---- degree counts ----
__global__ void k_deg(const int* __restrict__ dst, int* __restrict__ cnt, int E){
    int e = blockIdx.x*256 + threadIdx.x;
    if(e<E) atomicAdd(&cnt[dst[e]], 1);
}

// ---- scan + dinv, single block ----
__global__ __launch_bounds__(256) void k_scan(const int* __restrict__ cnt,
                                              int* __restrict__ rowptr, int* __restrict__ rowcur,
                                              float* __restrict__ dinv, int N, int E){
    __shared__ int part[256];
    int t = threadIdx.x;
    int C = (N+255)/256;
    int lo = t*C, hi = lo+C; if(hi>N) hi=N; if(lo>N) lo=N;
    int s=0;
    for(int i=lo;i<hi;i++) s += cnt[i];
    part[t]=s;
    __syncthreads();
    if(t==0){
        int run=0;
        for(int i=0;i<256;i++){ int v=part[i]; part[i]=run; run+=v; }
        rowptr[N]=E;
    }
    __syncthreads();
    int run = part[t];
    for(int i=lo;i<hi;i++){
        rowptr[i]=run; rowcur[i]=run; run += cnt[i];
        dinv[i] = rsqrtf((float)cnt[i] + 1.0f);
    }
}

__global__ void k_fill(const int* __restrict__ src, const int* __restrict__ dst,
                       const float* __restrict__ dinv, int* __restrict__ rowcur,
                       int* __restrict__ esrc, float* __restrict__ enorm, int E){
    int e = blockIdx.x*256 + threadIdx.x;
    if(e>=E) return;
    int s=src[e], d=dst[e];
    int pos = atomicAdd(&rowcur[d], 1);
    esrc[pos]=s;
    enorm[pos]=dinv[s]*dinv[d];
}

// ---- h1 = x @ W1 ----
__global__ __launch_bounds__(256) void k_h1(const float* __restrict__ x,
                                            const float* __restrict__ W1,
                                            float* __restrict__ h1, int N){
    __shared__ float wt[D1*NF];
    for(int idx=threadIdx.x; idx<NF*D1; idx+=256){
        int k=idx/D1, c=idx-k*D1;
        wt[c*NF+k]=W1[idx];
    }
    __syncthreads();
    int row = blockIdx.x*4 + (threadIdx.x>>6);
    int lane = threadIdx.x&63;
    if(row>=N) return;
    const float4* xr = (const float4*)(x + (size_t)row*NF);
    float acc[D1];
#pragma unroll
    for(int c=0;c<D1;c++) acc[c]=0.f;
#pragma unroll
    for(int i=0;i<3;i++){
        float4 v = xr[lane + 64*i];
#pragma unroll
        for(int c=0;c<D1;c++){
            float4 w = *(const float4*)&wt[c*NF + (lane+64*i)*4];
            acc[c] += v.x*w.x + v.y*w.y + v.z*w.z + v.w*w.w;
        }
    }
#pragma unroll
    for(int c=0;c<D1;c++){
        float v=acc[c];
#pragma unroll
        for(int off=32;off;off>>=1) v += __shfl_down(v,off,64);
        acc[c]=v;
    }
    if(lane==0){
#pragma unroll
        for(int c=0;c<D1;c++) h1[(size_t)row*D1+c]=acc[c];
    }
}

// ---- FUSED layer-1 gather + relu + hz = h @ W2 ----
__global__ __launch_bounds__(128) void k_gh(const float* __restrict__ h1,
        const int* __restrict__ rowptr, const int* __restrict__ esrc,
        const float* __restrict__ enorm, const float* __restrict__ dinv,
        const float* __restrict__ b1, const float* __restrict__ W2,
        float* __restrict__ hz, int N){
    __shared__ float w2s[D1*D2];
    int tid = threadIdx.x;
    for(int i=tid;i<D1*D2;i+=128) w2s[i]=W2[i];
    __syncthreads();
    int node = blockIdx.x*2 + (tid>>6);
    int lane = tid&63;
    if(node>=N) return;
    int e0=rowptr[node], e1=rowptr[node+1];
    float acc[D1];
#pragma unroll
    for(int c=0;c<D1;c++) acc[c]=0.f;
    for(int e=e0+lane; e<e1; e+=64){
        int s=esrc[e]; float w=enorm[e];
        const float* hr = h1 + (size_t)s*D1;
#pragma unroll
        for(int c=0;c<D1;c++) acc[c] += hr[c]*w;
    }
#pragma unroll
    for(int c=0;c<D1;c++){
        float v=acc[c];
#pragma unroll
        for(int off=32;off;off>>=1) v += __shfl_down(v,off,64);
        acc[c] = __shfl(v, 0, 64);
    }
    float di=dinv[node], d2=di*di;
    const float* hr = h1 + (size_t)node*D1;
    float h[D1];
#pragma unroll
    for(int c=0;c<D1;c++){
        float v = acc[c] + hr[c]*d2 + b1[c];
        h[c] = v>0.f ? v : 0.f;
    }
    float o0=0.f, o1=0.f;
#pragma unroll
    for(int k=0;k<D1;k++){
        o0 += h[k]*w2s[k*D2 + lane];
        o1 += h[k]*w2s[k*D2 + 64 + lane];
    }
    hz[(size_t)node*D2 + lane]      = o0;
    hz[(size_t)node*D2 + 64 + lane] = o1;
}

// ---- layer-2 CSR gather (fused zfin), fp32 z table ----
__global__ __launch_bounds__(128) void k_gath2(const float* __restrict__ hz,
        const int* __restrict__ rowptr, const int* __restrict__ esrc,
        const float* __restrict__ enorm, const float* __restrict__ dinv,
        const float* __restrict__ b2, float* __restrict__ zbf, int N){
    int n = blockIdx.x;
    int c = threadIdx.x;
    int e0 = rowptr[n], e1 = rowptr[n+1];
    float di = dinv[n];
    float acc = hz[(size_t)n*D2+c]*di*di + b2[c];
    int e = e0;
    for(; e+1<e1; e+=2){
        int s0=esrc[e], s1=esrc[e+1];
        float w0=enorm[e], w1=enorm[e+1];
        acc += hz[(size_t)s0*D2+c]*w0 + hz[(size_t)s1*D2+c]*w1;
    }
    if(e<e1) acc += hz[(size_t)esrc[e]*D2+c]*enorm[e];
    zbf[(size_t)n*D2+c] = acc;
}

// ---- B fragment image, K=768 (r_emb part only): 12 frags x 48 ks16 x 64 x 8 ----
__global__ void k_wimgB(const float* __restrict__ Wih, ushort* __restrict__ img,
                        int* __restrict__ cnt, int N){
    int gid = blockIdx.x*256 + threadIdx.x;        // 12*48*64 = 36864
    if(gid < N) cnt[gid] = 0;
    if(gid >= 12*48*64) return;
    int l = gid & 63;
    int ks16 = (gid>>6) % 48;
    int f = gid / (48*64);
    int dd = l & 31, kb = l>>5;
    int wn = f/3, gi = f - wn*3;
    int gbase = (gi==0)?0:((gi==1)?256:384);
    int wrow = gbase + wn*32 + dd;
    int k = ks16*16 + kb*8;
    const float* p = Wih + (size_t)wrow*1024 + 128 + k;
    float4 v0=*(const float4*)p, v1=*(const float4*)(p+4);
    ushort o[8];
    o[0]=f2bf(v0.x); o[1]=f2bf(v0.y); o[2]=f2bf(v0.z); o[3]=f2bf(v0.w);
    o[4]=f2bf(v1.x); o[5]=f2bf(v1.y); o[6]=f2bf(v1.z); o[7]=f2bf(v1.w);
    *(int4*)(img + (size_t)gid*8) = *(int4*)o;
}

// ---- zw B image: 24 frags x 8 ks16 x 64 lanes x 8 bf16 (combined zwh|zwt cols) ----
__global__ void k_wimgZ(const float* __restrict__ Wih, ushort* __restrict__ img){
    int gid = blockIdx.x*256 + threadIdx.x;        // 24*8*64 = 12288
    if(gid >= 24*8*64) return;
    int l = gid & 63;
    int ks16 = (gid>>6) & 7;
    int f = gid >> 9;
    int j = f*32 + (l&31);
    int kb = l>>5;
    int k = ks16*16 + kb*8;
    int jq = (j<384)? j : j-384;
    int wrow = (jq<128)? jq : jq+128;
    int wcol = (j<384)? k : (896+k);
    const float* p = Wih + (size_t)wrow*1024 + wcol;
    float4 v0=*(const float4*)p, v1=*(const float4*)(p+4);
    ushort o[8];
    o[0]=f2bf(v0.x); o[1]=f2bf(v0.y); o[2]=f2bf(v0.z); o[3]=f2bf(v0.w);
    o[4]=f2bf(v1.x); o[5]=f2bf(v1.y); o[6]=f2bf(v1.z); o[7]=f2bf(v1.w);
    *(int4*)(img + (size_t)gid*8) = *(int4*)o;
}

// ---- zwht = z @ [Wh|Wt] via MFMA, bf16 out. 32 nodes/block, 4 waves x 192 cols ----
__global__ __launch_bounds__(256) void k_zw_m(const float* __restrict__ z,
                                              const ushort* __restrict__ img,
                                              ushort* __restrict__ zwht, int N){
    __shared__ ushort As[8*64*8];     // 8 KB
    int tid=threadIdx.x, lane=tid&63, w=tid>>6;
    int n0 = blockIdx.x*32;
#pragma unroll
    for(int i=0;i<2;i++){
        int s = tid + 256*i;
        int ks16 = s>>6, l = s&63;
        int row = l&31, kb=l>>5;
        int n = n0+row; if(n>=N) n=N-1;
        const float* p = z + (size_t)n*D2 + ks16*16 + kb*8;
        float4 v0=*(const float4*)p, v1=*(const float4*)(p+4);
        ushort o[8];
        o[0]=f2bf(v0.x); o[1]=f2bf(v0.y); o[2]=f2bf(v0.z); o[3]=f2bf(v0.w);
        o[4]=f2bf(v1.x); o[5]=f2bf(v1.y); o[6]=f2bf(v1.z); o[7]=f2bf(v1.w);
        *(int4*)(&As[(size_t)s*8]) = *(int4*)o;
    }
    __syncthreads();
    f32x16 acc[6];
    const f32x16 zer = {0,0,0,0,0,0,0,0,0,0,0,0,0,0,0,0};
#pragma unroll
    for(int nf=0;nf<6;nf++) acc[nf]=zer;
#pragma unroll
    for(int ks16=0;ks16<8;ks16++){
        bf16x8 a = *(const bf16x8*)&As[(ks16*64+lane)*8];
#pragma unroll
        for(int nf=0;nf<6;nf++){
            int f = w*6+nf;
            bf16x8 b = *(const bf16x8*)(img + ((size_t)(f*8+ks16)*64 + lane)*8);
            acc[nf] = __builtin_amdgcn_mfma_f32_32x32x16_bf16(a,b,acc[nf],0,0,0);
        }
    }
    int l31=lane&31, lh=lane>>5;
#pragma unroll
    for(int nf=0;nf<6;nf++){
        int j = (w*6+nf)*32 + l31;
#pragma unroll
        for(int r=0;r<16;r++){
            int row = (r&3)+8*(r>>2)+4*lh;
            int n = n0+row;
            if(n<N) zwht[(size_t)n*768 + j] = (ushort)f2bf(acc[nf][r]);
        }
    }
}

// ---- fused MFMA GEMM (K=768, r_emb only) + z-table gather + LSTM partials.
// 4 waves, BK=32 (24 steps). A reg->cvt->LDS ring-2; B gload_lds ring-2;
// one barrier + vmcnt(2) per step (queue never drains mid-loop). ----
__global__ __launch_bounds__(256,2) void k_big(
    const float* __restrict__ remb, const ushort* __restrict__ img,
    const ushort* __restrict__ zwht, const float* __restrict__ b_ih,
    const float* __restrict__ b_hh, const int* __restrict__ trip,
    float* __restrict__ rowacc, int T)
{
    __shared__ ushort Ab[2][4*64*8];     // 2 x 4 KB: [slot][(s2*2+kh)*64+row][8]
    __shared__ ushort Br[2][24*512];     // 2 x 24 KB: [slot][(f*2+s2)*512 + lane*8]
    __shared__ int sh_th[BM], sh_tt[BM];
    int tid=threadIdx.x, lane=tid&63, w=tid>>6;
    int l31=lane&31, lh=lane>>5;
    int t0=blockIdx.x*BM;

    if(tid<BM){
        int t=t0+tid, tc=(t<T)?t:T-1;
        sh_th[tid]=trip[3*tc]; sh_tt[tid]=trip[3*tc+2];
    }

    // A staging: row = w*16 + (lane>>2), asub = lane&3 (16B k-seg within 16)
    const int arow = w*16 + (lane>>2);
    const int asub = lane&3;
    int tc = t0 + arow; if(tc>=T) tc=T-1;
    const float* prm = remb + (size_t)tc*NF + asub*4;
    // write offsets (ushort units) for the two 16-k halves (s2=0,1)
    const int aw0 = ((0*2 + (asub>>1))*64 + arow)*8 + (asub&1)*4;
    const int aw1 = ((1*2 + (asub>>1))*64 + arow)*8 + (asub&1)*4;
    // frag read bases
    const int ar00 = ((0*2+lh)*64 + l31)*8,      ar01 = ((0*2+lh)*64 + 32 + l31)*8;
    const int ar10 = ((1*2+lh)*64 + l31)*8,      ar11 = ((1*2+lh)*64 + 32 + l31)*8;

    f32x16 acc[2][3];
    const f32x16 zer = {0,0,0,0,0,0,0,0,0,0,0,0,0,0,0,0};
#pragma unroll
    for(int m=0;m<2;m++)
#pragma unroll
        for(int g=0;g<3;g++) acc[m][g]=zer;

    float4 pa[2][2];

#define ALOAD(C_) if((C_)<24){ \
    pa[(C_)&1][0] = *(const float4*)(prm + (C_)*32); \
    pa[(C_)&1][1] = *(const float4*)(prm + (C_)*32 + 16); }

#define AWRITE(C_) if((C_)<24){ \
    *(short4*)&Ab[(C_)&1][aw0] = cvt4(pa[(C_)&1][0]); \
    *(short4*)&Ab[(C_)&1][aw1] = cvt4(pa[(C_)&1][1]); }

#define BISSUE(C_) if((C_)<24){ \
    _Pragma("unroll") \
    for(int j_=0;j_<6;j_++){ \
        int f_ = w*3 + (j_>>1), s_ = j_&1; \
        gload16(img + ((size_t)(f_*48 + (C_)*2 + s_)*64 + lane)*8, \
                &Br[(C_)&1][(f_*2+s_)*512]); \
    } }

#define CH(C_,W_) { \
    asm volatile("s_waitcnt vmcnt(" W_ ")" ::: "memory"); \
    __builtin_amdgcn_sched_barrier(0); \
    asm volatile("s_waitcnt lgkmcnt(0)" ::: "memory"); \
    __builtin_amdgcn_s_barrier(); \
    __builtin_amdgcn_sched_barrier(0); \
    BISSUE((C_)+1) \
    ALOAD((C_)+2) \
    __builtin_amdgcn_sched_barrier(0); \
    { \
        const ushort* a_ = &Ab[(C_)&1][0]; \
        const ushort* b_ = &Br[(C_)&1][0]; \
        bf16x8 A00 = *(const bf16x8*)&a_[ar00]; \
        bf16x8 A01 = *(const bf16x8*)&a_[ar01]; \
        bf16x8 B00 = *(const bf16x8*)&b_[((w*3+0)*2+0)*512 + lane*8]; \
        bf16x8 B01 = *(const bf16x8*)&b_[((w*3+1)*2+0)*512 + lane*8]; \
        bf16x8 B02 = *(const bf16x8*)&b_[((w*3+2)*2+0)*512 + lane*8]; \
        __builtin_amdgcn_s_setprio(1); \
        acc[0][0]=__builtin_amdgcn_mfma_f32_32x32x16_bf16(A00,B00,acc[0][0],0,0,0); \
        acc[0][1]=__builtin_amdgcn_mfma_f32_32x32x16_bf16(A00,B01,acc[0][1],0,0,0); \
        acc[0][2]=__builtin_amdgcn_mfma_f32_32x32x16_bf16(A00,B02,acc[0][2],0,0,0); \
        acc[1][0]=__builtin_amdgcn_mfma_f32_32x32x16_bf16(A01,B00,acc[1][0],0,0,0); \
        acc[1][1]=__builtin_amdgcn_mfma_f32_32x32x16_bf16(A01,B01,acc[1][1],0,0,0); \
        acc[1][2]=__builtin_amdgcn_mfma_f32_32x32x16_bf16(A01,B02,acc[1][2],0,0,0); \
        __builtin_amdgcn_s_setprio(0); \
        bf16x8 A10 = *(const bf16x8*)&a_[ar10]; \
        bf16x8 A11 = *(const bf16x8*)&a_[ar11]; \
        bf16x8 B10 = *(const bf16x8*)&b_[((w*3+0)*2+1)*512 + lane*8]; \
        bf16x8 B11 = *(const bf16x8*)&b_[((w*3+1)*2+1)*512 + lane*8]; \
        bf16x8 B12 = *(const bf16x8*)&b_[((w*3+2)*2+1)*512 + lane*8]; \
        __builtin_amdgcn_s_setprio(1); \
        acc[0][0]=__builtin_amdgcn_mfma_f32_32x32x16_bf16(A10,B10,acc[0][0],0,0,0); \
        acc[0][1]=__builtin_amdgcn_mfma_f32_32x32x16_bf16(A10,B11,acc[0][1],0,0,0); \
        acc[0][2]=__builtin_amdgcn_mfma_f32_32x32x16_bf16(A10,B12,acc[0][2],0,0,0); \
        acc[1][0]=__builtin_amdgcn_mfma_f32_32x32x16_bf16(A11,B10,acc[1][0],0,0,0); \
        acc[1][1]=__builtin_amdgcn_mfma_f32_32x32x16_bf16(A11,B11,acc[1][1],0,0,0); \
        acc[1][2]=__builtin_amdgcn_mfma_f32_32x32x16_bf16(A11,B12,acc[1][2],0,0,0); \
        __builtin_amdgcn_s_setprio(0); \
    } \
    AWRITE((C_)+1) \
}

    // prologue: A(0), B(0), A(1); write A(0)
    ALOAD(0)
    __builtin_amdgcn_sched_barrier(0);
    BISSUE(0)
    ALOAD(1)
    __builtin_amdgcn_sched_barrier(0);
    AWRITE(0)

    CH(0 ,"2") CH(1 ,"2") CH(2 ,"2") CH(3 ,"2") CH(4 ,"2") CH(5 ,"2")
    CH(6 ,"2") CH(7 ,"2") CH(8 ,"2") CH(9 ,"2") CH(10,"2") CH(11,"2")
    CH(12,"2") CH(13,"2") CH(14,"2") CH(15,"2") CH(16,"2") CH(17,"2")
    CH(18,"2") CH(19,"2") CH(20,"2") CH(21,"2") CH(22,"2") CH(23,"0")
#undef CH
#undef BISSUE
#undef AWRITE
#undef ALOAD

    // ---- epilogue: z-table gather + bias + LSTM + row-sum partials ----
    int d = w*32+l31;
    float bi=b_ih[d]+b_hh[d];
    float bg=b_ih[256+d]+b_hh[256+d];
    float bo=b_ih[384+d]+b_hh[384+d];
#pragma unroll
    for(int m=0;m<2;m++){
#pragma unroll
        for(int r=0;r<16;r++){
            int row = m*32 + (r&3)+8*(r>>2)+4*lh;
            int t = t0+row;
            float ov = 0.f;
            if(t<T){
                const ushort* zh = zwht + (size_t)sh_th[row]*768;
                const ushort* zt = zwht + (size_t)sh_tt[row]*768 + 384;
                float ig = acc[m][0][r] + bf2f(zh[d])     + bf2f(zt[d])     + bi;
                float gg = acc[m][1][r] + bf2f(zh[128+d]) + bf2f(zt[128+d]) + bg;
                float og = acc[m][2][r] + bf2f(zh[256+d]) + bf2f(zt[256+d]) + bo;
                float cc = sigf(ig)*tanhfast(gg);
                ov = sigf(og)*tanhfast(cc);
            }
#pragma unroll
            for(int off=1; off<32; off<<=1) ov += __shfl_xor(ov, off, 64);
            if(l31==0 && t<T) atomicAdd(&rowacc[t], ov);
        }
    }
}

__global__ void k_sig(const float* __restrict__ rowacc, float* __restrict__ score, int T){
    int t = blockIdx.x*256 + threadIdx.x;
    if(t<T) score[t] = sigf(rowacc[t]);
}

extern "C" void kernel_launch(void* const* d_in, const int* in_sizes, int n_in,
                              void* d_out, int out_size, void* d_ws, size_t ws_size,
                              hipStream_t stream){
    const float* x    = (const float*)d_in[0];
    const float* remb = (const float*)d_in[1];
    const float* W1   = (const float*)d_in[2];
    const float* b1   = (const float*)d_in[3];
    const float* W2   = (const float*)d_in[4];
    const float* b2   = (const float*)d_in[5];
    const float* Wih  = (const float*)d_in[6];
    const float* b_ih = (const float*)d_in[8];
    const float* b_hh = (const float*)d_in[9];
    const int*   ei   = (const int*)d_in[10];
    const int*   trip = (const int*)d_in[11];
    float* score = (float*)d_out;

    const int N = in_sizes[0]/NF;       // 15000
    const int E = in_sizes[10]/2;       // 200000
    const int T = in_sizes[11]/3;       // 100000
    const int* src = ei;
    const int* dst = ei + E;

    float* ws = (float*)d_ws;
    size_t o = 0;
    ushort* img   = (ushort*)(ws+o); o += (size_t)12*48*64*8/2;  // 590 KB
    ushort* imgZ  = (ushort*)(ws+o); o += (size_t)24*8*64*8/2;   // 196 KB
    ushort* zwht  = (ushort*)(ws+o); o += (size_t)N*768/2;       // 23 MB bf16
    float* zbf    = ws+o;            o += (size_t)N*D2;          // fp32 z
    float* rowacc = ws+o;            o += (size_t)((T+7)&~7);
    int*   cnt    = (int*)(ws+o);    o += (size_t)((N+8)&~7);
    int*   rowptr = (int*)(ws+o);    o += (size_t)((N+8)&~7);
    int*   rowcur = (int*)(ws+o);    o += (size_t)((N+8)&~7);
    int*   esrc   = (int*)(ws+o);    o += (size_t)E;
    float* enorm  = ws+o;            o += (size_t)E;
    float* dinv   = ws+o;            o += (size_t)((N+7)&~7);
    float* h1     = ws+o;            o += (size_t)N*D1;
    float* hz     = ws+o;            o += (size_t)N*D2;
    (void)ws_size; (void)n_in; (void)out_size;

    hipMemsetAsync(rowacc, 0, (size_t)T*sizeof(float), stream);

    k_wimgB<<<dim3((12*48*64+255)/256), dim3(256), 0, stream>>>(Wih, img, cnt, N);
    k_wimgZ<<<dim3((24*8*64+255)/256),  dim3(256), 0, stream>>>(Wih, imgZ);
    k_deg  <<<dim3((E+255)/256), dim3(256), 0, stream>>>(dst, cnt, E);
    k_scan <<<dim3(1), dim3(256), 0, stream>>>(cnt, rowptr, rowcur, dinv, N, E);
    k_fill <<<dim3((E+255)/256), dim3(256), 0, stream>>>(src, dst, dinv, rowcur, esrc, enorm, E);
    k_h1   <<<dim3((N+3)/4), dim3(256), 0, stream>>>(x, W1, h1, N);
    k_gh   <<<dim3((N+1)/2), dim3(128), 0, stream>>>(h1, rowptr, esrc, enorm, dinv, b1, W2, hz, N);
    k_gath2<<<dim3(N), dim3(128), 0, stream>>>(hz, rowptr, esrc, enorm, dinv, b2, zbf, N);
    k_zw_m <<<dim3((N+31)/32), dim3(256), 0, stream>>>(zbf, imgZ, zwht, N);
    k_big  <<<dim3((T+BM-1)/BM), dim3(256), 0, stream>>>(remb, img, zwht, b_ih, b_hh, trip, rowacc, T);
    k_sig  <<<dim3((T+255)/256), dim3(256), 0, stream>>>(rowacc, score, T);
}

// Round 17
// 306.601 us; speedup vs baseline: 1.2001x; 1.2001x over previous
//
#include <hip/hip_runtime.h>

#define NF 768
#define D1 10
#define D2 128
#define BM 64

typedef __attribute__((ext_vector_type(8))) short bf16x8;
typedef __attribute__((ext_vector_type(16))) float f32x16;

static __device__ __forceinline__ float sigf(float v){ return 1.0f/(1.0f+__expf(-v)); }
static __device__ __forceinline__ float tanhfast(float v){ return 2.0f/(1.0f+__expf(-2.0f*v)) - 1.0f; }
static __device__ __forceinline__ short f2bf(float f){
    unsigned u = __float_as_uint(f);
    u += 0x7fffu + ((u>>16)&1u);
    return (short)(u>>16);
}

static __device__ __forceinline__ short4 cvt4(float4 a){
    unsigned u0,u1;
    asm("v_cvt_pk_bf16_f32 %0, %1, %2" : "=v"(u0) : "v"(a.x), "v"(a.y));
    asm("v_cvt_pk_bf16_f32 %0, %1, %2" : "=v"(u1) : "v"(a.z), "v"(a.w));
    union { unsigned u[2]; short4 s; } r;
    r.u[0]=u0; r.u[1]=u1;
    return r.s;
}

// ---- degree counts ----
__global__ void k_deg(const int* __restrict__ dst, int* __restrict__ cnt, int E){
    int e = blockIdx.x*256 + threadIdx.x;
    if(e<E) atomicAdd(&cnt[dst[e]], 1);
}

// ---- scan + dinv, single block ----
__global__ __launch_bounds__(256) void k_scan(const int* __restrict__ cnt,
                                              int* __restrict__ rowptr, int* __restrict__ rowcur,
                                              float* __restrict__ dinv, int N, int E){
    __shared__ int part[256];
    int t = threadIdx.x;
    int C = (N+255)/256;
    int lo = t*C, hi = lo+C; if(hi>N) hi=N; if(lo>N) lo=N;
    int s=0;
    for(int i=lo;i<hi;i++) s += cnt[i];
    part[t]=s;
    __syncthreads();
    if(t==0){
        int run=0;
        for(int i=0;i<256;i++){ int v=part[i]; part[i]=run; run+=v; }
        rowptr[N]=E;
    }
    __syncthreads();
    int run = part[t];
    for(int i=lo;i<hi;i++){
        rowptr[i]=run; rowcur[i]=run; run += cnt[i];
        dinv[i] = rsqrtf((float)cnt[i] + 1.0f);
    }
}

__global__ void k_fill(const int* __restrict__ src, const int* __restrict__ dst,
                       const float* __restrict__ dinv, int* __restrict__ rowcur,
                       int* __restrict__ esrc, float* __restrict__ enorm, int E){
    int e = blockIdx.x*256 + threadIdx.x;
    if(e>=E) return;
    int s=src[e], d=dst[e];
    int pos = atomicAdd(&rowcur[d], 1);
    esrc[pos]=s;
    enorm[pos]=dinv[s]*dinv[d];
}

// ---- h1 = x @ W1 ----
__global__ __launch_bounds__(256) void k_h1(const float* __restrict__ x,
                                            const float* __restrict__ W1,
                                            float* __restrict__ h1, int N){
    __shared__ float wt[D1*NF];
    for(int idx=threadIdx.x; idx<NF*D1; idx+=256){
        int k=idx/D1, c=idx-k*D1;
        wt[c*NF+k]=W1[idx];
    }
    __syncthreads();
    int row = blockIdx.x*4 + (threadIdx.x>>6);
    int lane = threadIdx.x&63;
    if(row>=N) return;
    const float4* xr = (const float4*)(x + (size_t)row*NF);
    float acc[D1];
#pragma unroll
    for(int c=0;c<D1;c++) acc[c]=0.f;
#pragma unroll
    for(int i=0;i<3;i++){
        float4 v = xr[lane + 64*i];
#pragma unroll
        for(int c=0;c<D1;c++){
            float4 w = *(const float4*)&wt[c*NF + (lane+64*i)*4];
            acc[c] += v.x*w.x + v.y*w.y + v.z*w.z + v.w*w.w;
        }
    }
#pragma unroll
    for(int c=0;c<D1;c++){
        float v=acc[c];
#pragma unroll
        for(int off=32;off;off>>=1) v += __shfl_down(v,off,64);
        acc[c]=v;
    }
    if(lane==0){
#pragma unroll
        for(int c=0;c<D1;c++) h1[(size_t)row*D1+c]=acc[c];
    }
}

// ---- FUSED layer-1 gather + relu + hz = h @ W2 ----
__global__ __launch_bounds__(128) void k_gh(const float* __restrict__ h1,
        const int* __restrict__ rowptr, const int* __restrict__ esrc,
        const float* __restrict__ enorm, const float* __restrict__ dinv,
        const float* __restrict__ b1, const float* __restrict__ W2,
        float* __restrict__ hz, int N){
    __shared__ float w2s[D1*D2];
    int tid = threadIdx.x;
    for(int i=tid;i<D1*D2;i+=128) w2s[i]=W2[i];
    __syncthreads();
    int node = blockIdx.x*2 + (tid>>6);
    int lane = tid&63;
    if(node>=N) return;
    int e0=rowptr[node], e1=rowptr[node+1];
    float acc[D1];
#pragma unroll
    for(int c=0;c<D1;c++) acc[c]=0.f;
    for(int e=e0+lane; e<e1; e+=64){
        int s=esrc[e]; float w=enorm[e];
        const float* hr = h1 + (size_t)s*D1;
#pragma unroll
        for(int c=0;c<D1;c++) acc[c] += hr[c]*w;
    }
#pragma unroll
    for(int c=0;c<D1;c++){
        float v=acc[c];
#pragma unroll
        for(int off=32;off;off>>=1) v += __shfl_down(v,off,64);
        acc[c] = __shfl(v, 0, 64);
    }
    float di=dinv[node], d2=di*di;
    const float* hr = h1 + (size_t)node*D1;
    float h[D1];
#pragma unroll
    for(int c=0;c<D1;c++){
        float v = acc[c] + hr[c]*d2 + b1[c];
        h[c] = v>0.f ? v : 0.f;
    }
    float o0=0.f, o1=0.f;
#pragma unroll
    for(int k=0;k<D1;k++){
        o0 += h[k]*w2s[k*D2 + lane];
        o1 += h[k]*w2s[k*D2 + 64 + lane];
    }
    hz[(size_t)node*D2 + lane]      = o0;
    hz[(size_t)node*D2 + 64 + lane] = o1;
}

// ---- layer-2 CSR gather (fused zfin), fp32 z table ----
__global__ __launch_bounds__(128) void k_gath2(const float* __restrict__ hz,
        const int* __restrict__ rowptr, const int* __restrict__ esrc,
        const float* __restrict__ enorm, const float* __restrict__ dinv,
        const float* __restrict__ b2, float* __restrict__ zbf, int N){
    int n = blockIdx.x;
    int c = threadIdx.x;
    int e0 = rowptr[n], e1 = rowptr[n+1];
    float di = dinv[n];
    float acc = hz[(size_t)n*D2+c]*di*di + b2[c];
    int e = e0;
    for(; e+1<e1; e+=2){
        int s0=esrc[e], s1=esrc[e+1];
        float w0=enorm[e], w1=enorm[e+1];
        acc += hz[(size_t)s0*D2+c]*w0 + hz[(size_t)s1*D2+c]*w1;
    }
    if(e<e1) acc += hz[(size_t)esrc[e]*D2+c]*enorm[e];
    zbf[(size_t)n*D2+c] = acc;
}

// ---- B fragment image K=1024 (+ zero cnt): 12 frags x 64 ks16 x 64 x 8 ----
__global__ void k_wimgB(const float* __restrict__ Wih, ushort* __restrict__ img,
                        int* __restrict__ cnt, int N){
    int gid = blockIdx.x*256 + threadIdx.x;        // 12*64*64 = 49152
    if(gid < N) cnt[gid] = 0;
    if(gid >= 12*64*64) return;
    int l = gid & 63;
    int ks16 = (gid>>6) & 63;
    int f = gid >> 12;
    int dd = l & 31, kb = l>>5;
    int wn = f/3, gi = f - wn*3;
    int gbase = (gi==0)?0:((gi==1)?256:384);
    int wrow = gbase + wn*32 + dd;
    int k = ks16*16 + kb*8;
    const float* p = Wih + (size_t)wrow*1024 + k;
    float4 v0=*(const float4*)p, v1=*(const float4*)(p+4);
    ushort o[8];
    o[0]=f2bf(v0.x); o[1]=f2bf(v0.y); o[2]=f2bf(v0.z); o[3]=f2bf(v0.w);
    o[4]=f2bf(v1.x); o[5]=f2bf(v1.y); o[6]=f2bf(v1.z); o[7]=f2bf(v1.w);
    *(int4*)(img + (size_t)gid*8) = *(int4*)o;
}

// ---- fused MFMA GEMM + LSTM partials. r15 skeleton, but B = direct L2->register
// ring-2 (no LDS round-trip: -24KB LDS traffic/block-step, the measured top term).
// A: reg ring-4 -> cvt -> conflict-free LDS ring-3. No manual vmcnt (all loads
// compiler-managed; A ring-4 keeps the HBM queue >= 1-step deep under B's waits).
// One raw barrier + lgkmcnt(0) + sched_barrier per step (rule #18). ----
__global__ __launch_bounds__(256,2) void k_big(
    const float* __restrict__ remb, const ushort* __restrict__ img,
    const float* __restrict__ zbf, const float* __restrict__ b_ih,
    const float* __restrict__ b_hh, const int* __restrict__ trip,
    float* __restrict__ rowacc, int T)
{
    __shared__ ushort Ab[3][2*64*8];     // 3 x 2 KB: [ring][kh*64+row][8 bf16]
    int tid=threadIdx.x, lane=tid&63, w=tid>>6;
    int l31=lane&31, lh=lane>>5;
    int t0=blockIdx.x*BM;

    // A staging: lane -> row = w*16 + (lane>>2), asub = lane&3 (16B k-seg)
    const int arow = w*16 + (lane>>2);
    const int asub = lane&3;
    int tc = t0 + arow; if(tc>=T) tc=T-1;
    const float* pzh = zbf + (size_t)trip[3*tc]*D2   + asub*4;
    const float* prm = remb + (size_t)tc*NF          + asub*4;
    const float* pzt = zbf + (size_t)trip[3*tc+2]*D2 + asub*4;
    const int awoff = ((asub>>1)*64 + arow)*8 + (asub&1)*4;
    const int ar0 = (lh*64 + l31)*8;
    const int ar1 = (lh*64 + 32 + l31)*8;

    const ushort* wb0 = img + ((size_t)((w*3+0)*64)*64 + lane)*8;
    const ushort* wb1 = img + ((size_t)((w*3+1)*64)*64 + lane)*8;
    const ushort* wb2 = img + ((size_t)((w*3+2)*64)*64 + lane)*8;

    f32x16 acc[2][3];
    const f32x16 zer = {0,0,0,0,0,0,0,0,0,0,0,0,0,0,0,0};
#pragma unroll
    for(int m=0;m<2;m++)
#pragma unroll
        for(int g=0;g<3;g++) acc[m][g]=zer;

    float4 pa[4];
    bf16x8 qb[2][3];

#define ALOAD(C_) if((C_)<64){ \
    const float* s_; \
    if((C_)<8)       s_ = pzh + (C_)*16; \
    else if((C_)<56) s_ = prm + ((C_)-8)*16; \
    else             s_ = pzt + ((C_)-56)*16; \
    pa[(C_)&3] = *(const float4*)s_; }

#define AWRITE(C_) if((C_)<64){ \
    *(short4*)&Ab[(C_)%3][awoff] = cvt4(pa[(C_)&3]); }

#define BLOAD(C_) if((C_)<64){ \
    qb[(C_)&1][0] = *(const bf16x8*)(wb0 + (size_t)(C_)*512); \
    qb[(C_)&1][1] = *(const bf16x8*)(wb1 + (size_t)(C_)*512); \
    qb[(C_)&1][2] = *(const bf16x8*)(wb2 + (size_t)(C_)*512); }

#define CH(C_) { \
    BLOAD((C_)+1) \
    ALOAD((C_)+4) \
    __builtin_amdgcn_sched_barrier(0); \
    AWRITE((C_)+1) \
    asm volatile("s_waitcnt lgkmcnt(0)" ::: "memory"); \
    __builtin_amdgcn_s_barrier(); \
    __builtin_amdgcn_sched_barrier(0); \
    { \
        const ushort* a_ = &Ab[(C_)%3][0]; \
        bf16x8 A0_ = *(const bf16x8*)&a_[ar0]; \
        bf16x8 A1_ = *(const bf16x8*)&a_[ar1]; \
        bf16x8 B0_ = qb[(C_)&1][0]; \
        bf16x8 B1_ = qb[(C_)&1][1]; \
        bf16x8 B2_ = qb[(C_)&1][2]; \
        __builtin_amdgcn_s_setprio(1); \
        acc[0][0]=__builtin_amdgcn_mfma_f32_32x32x16_bf16(A0_,B0_,acc[0][0],0,0,0); \
        acc[0][1]=__builtin_amdgcn_mfma_f32_32x32x16_bf16(A0_,B1_,acc[0][1],0,0,0); \
        acc[0][2]=__builtin_amdgcn_mfma_f32_32x32x16_bf16(A0_,B2_,acc[0][2],0,0,0); \
        acc[1][0]=__builtin_amdgcn_mfma_f32_32x32x16_bf16(A1_,B0_,acc[1][0],0,0,0); \
        acc[1][1]=__builtin_amdgcn_mfma_f32_32x32x16_bf16(A1_,B1_,acc[1][1],0,0,0); \
        acc[1][2]=__builtin_amdgcn_mfma_f32_32x32x16_bf16(A1_,B2_,acc[1][2],0,0,0); \
        __builtin_amdgcn_s_setprio(0); \
    } \
}

    // prologue: A(0..3) in regs, B(0), write A(0) into Ab[0]
    ALOAD(0) ALOAD(1) ALOAD(2) ALOAD(3)
    __builtin_amdgcn_sched_barrier(0);
    BLOAD(0)
    __builtin_amdgcn_sched_barrier(0);
    AWRITE(0)

    CH(0)  CH(1)  CH(2)  CH(3)  CH(4)  CH(5)  CH(6)  CH(7)
    CH(8)  CH(9)  CH(10) CH(11) CH(12) CH(13) CH(14) CH(15)
    CH(16) CH(17) CH(18) CH(19) CH(20) CH(21) CH(22) CH(23)
    CH(24) CH(25) CH(26) CH(27) CH(28) CH(29) CH(30) CH(31)
    CH(32) CH(33) CH(34) CH(35) CH(36) CH(37) CH(38) CH(39)
    CH(40) CH(41) CH(42) CH(43) CH(44) CH(45) CH(46) CH(47)
    CH(48) CH(49) CH(50) CH(51) CH(52) CH(53) CH(54) CH(55)
    CH(56) CH(57) CH(58) CH(59) CH(60) CH(61) CH(62) CH(63)
#undef CH
#undef BLOAD
#undef AWRITE
#undef ALOAD

    // ---- epilogue: bias + LSTM + partial row-sums (global atomics) ----
    int d = w*32+l31;
    float bi=b_ih[d]+b_hh[d];
    float bg=b_ih[256+d]+b_hh[256+d];
    float bo=b_ih[384+d]+b_hh[384+d];
#pragma unroll
    for(int m=0;m<2;m++){
#pragma unroll
        for(int r=0;r<16;r++){
            int row = m*32 + (r&3)+8*(r>>2)+4*lh;
            int t = t0+row;
            float ov = 0.f;
            if(t<T){
                float ig = acc[m][0][r] + bi;
                float gg = acc[m][1][r] + bg;
                float og = acc[m][2][r] + bo;
                float cc = sigf(ig)*tanhfast(gg);
                ov = sigf(og)*tanhfast(cc);
            }
#pragma unroll
            for(int off=1; off<32; off<<=1) ov += __shfl_xor(ov, off, 64);
            if(l31==0 && t<T) atomicAdd(&rowacc[t], ov);
        }
    }
}

__global__ void k_sig(const float* __restrict__ rowacc, float* __restrict__ score, int T){
    int t = blockIdx.x*256 + threadIdx.x;
    if(t<T) score[t] = sigf(rowacc[t]);
}

extern "C" void kernel_launch(void* const* d_in, const int* in_sizes, int n_in,
                              void* d_out, int out_size, void* d_ws, size_t ws_size,
                              hipStream_t stream){
    const float* x    = (const float*)d_in[0];
    const float* remb = (const float*)d_in[1];
    const float* W1   = (const float*)d_in[2];
    const float* b1   = (const float*)d_in[3];
    const float* W2   = (const float*)d_in[4];
    const float* b2   = (const float*)d_in[5];
    const float* Wih  = (const float*)d_in[6];
    const float* b_ih = (const float*)d_in[8];
    const float* b_hh = (const float*)d_in[9];
    const int*   ei   = (const int*)d_in[10];
    const int*   trip = (const int*)d_in[11];
    float* score = (float*)d_out;

    const int N = in_sizes[0]/NF;       // 15000
    const int E = in_sizes[10]/2;       // 200000
    const int T = in_sizes[11]/3;       // 100000
    const int* src = ei;
    const int* dst = ei + E;

    float* ws = (float*)d_ws;
    size_t o = 0;
    ushort* img   = (ushort*)(ws+o); o += (size_t)12*64*64*8/2;  // 786 KB
    float* zbf    = ws+o;            o += (size_t)N*D2;          // fp32 z
    float* rowacc = ws+o;            o += (size_t)((T+7)&~7);
    int*   cnt    = (int*)(ws+o);    o += (size_t)((N+8)&~7);
    int*   rowptr = (int*)(ws+o);    o += (size_t)((N+8)&~7);
    int*   rowcur = (int*)(ws+o);    o += (size_t)((N+8)&~7);
    int*   esrc   = (int*)(ws+o);    o += (size_t)E;
    float* enorm  = ws+o;            o += (size_t)E;
    float* dinv   = ws+o;            o += (size_t)((N+7)&~7);
    float* h1     = ws+o;            o += (size_t)N*D1;
    float* hz     = ws+o;            o += (size_t)N*D2;
    (void)ws_size; (void)n_in; (void)out_size;

    hipMemsetAsync(rowacc, 0, (size_t)T*sizeof(float), stream);

    k_wimgB<<<dim3((12*64*64+255)/256), dim3(256), 0, stream>>>(Wih, img, cnt, N);
    k_deg  <<<dim3((E+255)/256), dim3(256), 0, stream>>>(dst, cnt, E);
    k_scan <<<dim3(1), dim3(256), 0, stream>>>(cnt, rowptr, rowcur, dinv, N, E);
    k_fill <<<dim3((E+255)/256), dim3(256), 0, stream>>>(src, dst, dinv, rowcur, esrc, enorm, E);
    k_h1   <<<dim3((N+3)/4), dim3(256), 0, stream>>>(x, W1, h1, N);
    k_gh   <<<dim3((N+1)/2), dim3(128), 0, stream>>>(h1, rowptr, esrc, enorm, dinv, b1, W2, hz, N);
    k_gath2<<<dim3(N), dim3(128), 0, stream>>>(hz, rowptr, esrc, enorm, dinv, b2, zbf, N);
    k_big  <<<dim3((T+BM-1)/BM), dim3(256), 0, stream>>>(remb, img, zbf, b_ih, b_hh, trip, rowacc, T);
    k_sig  <<<dim3((T+255)/256), dim3(256), 0, stream>>>(rowacc, score, T);
}